// Round 1
// baseline (400.404 us; speedup 1.0000x reference)
//
#include <hip/hip_runtime.h>

#define NTOT 196608
#define BAGS 4096
#define H 230
#define H3 690
#define NC 53

// tanh(x) = 1 - 2/(exp(2x)+1), v_rcp instead of precise division.
// Saturates correctly at +/-1 for large |x|.
__device__ __forceinline__ float fast_tanh(float x) {
    float e = __expf(2.f * x);
    float r = __builtin_amdgcn_rcpf(e + 1.f);
    return fmaf(-2.f, r, 1.f);
}

// ---------------------------------------------------------------------------
// Kernel 0: per-class table (53 classes).
// cls[0*NC+c] = logit const k=0, cls[1*NC+c] = logit const k=1,
// cls[2*NC+c] = vsm0, cls[3*NC+c] = vsm1
// ---------------------------------------------------------------------------
__global__ void class_table_kernel(const float* __restrict__ rel_emb0,
                                   const float* __restrict__ rel_emb1,
                                   const float* __restrict__ att_w0,
                                   const float* __restrict__ att_w1,
                                   const float* __restrict__ w_s,
                                   const float* __restrict__ b_s,
                                   const int* __restrict__ relation_levels,
                                   float* __restrict__ cls)
{
    int c = blockIdx.x;
    int lane = threadIdx.x;  // 64 threads
    int l0 = relation_levels[c * 2 + 0];
    int l1 = relation_levels[c * 2 + 1];
    float a00 = 0.f, a01 = 0.f, a10 = 0.f, a11 = 0.f;
    for (int j = lane; j < H; j += 64) {
        float t0 = fast_tanh(rel_emb0[l0 * H + j]);
        float t1 = fast_tanh(rel_emb1[l1 * H + j]);
        a00 += w_s[0 * H3 + H + j] * t0;
        a01 += w_s[0 * H3 + 2 * H + j] * t1;
        a10 += w_s[1 * H3 + H + j] * t0;
        a11 += w_s[1 * H3 + 2 * H + j] * t1;
    }
    for (int m = 32; m; m >>= 1) {
        a00 += __shfl_xor(a00, m);
        a01 += __shfl_xor(a01, m);
        a10 += __shfl_xor(a10, m);
        a11 += __shfl_xor(a11, m);
    }
    if (lane == 0) {
        cls[0 * NC + c] = a00 + a01 + b_s[0];
        cls[1 * NC + c] = a10 + a11 + b_s[1];
        float v0 = att_w0[l0], v1 = att_w1[l1];
        float mx = fmaxf(v0, v1);
        float e0 = __expf(v0 - mx), e1 = __expf(v1 - mx);
        float rz = __builtin_amdgcn_rcpf(e0 + e1);
        cls[2 * NC + c] = e0 * rz;
        cls[3 * NC + c] = e1 * rz;
    }
}

// ---------------------------------------------------------------------------
// Kernel 1: one block per bag, SINGLE pass over x.
// Changes vs previous version:
//  * float2 loads (every row is 8B-aligned: 230*4 = 920 % 8 == 0)
//  * cnt==48 fast path: fully unrolled 12-instance loop with a 2-deep
//    rotating prefetch (row t+2 + label t+2 issued while computing t), so
//    HBM latency hides under two tanh/butterfly bodies.
//  * __launch_bounds__(256,6): 85-VGPR budget (the old (256,8)=64 cap risked
//    scratch spills inside the hot loop), 6 blocks/CU = 24 waves/CU.
// Lane mapping: u=0 -> elements 2*lane, 2*lane+1 (j in [0,128));
//               u=1 -> elements 128+2*lane (lane<51, j in [128,230)).
// ---------------------------------------------------------------------------
__global__ __launch_bounds__(256, 6) void bag_kernel(
    const float* __restrict__ x,
    const float* __restrict__ w_s,
    const float* __restrict__ disc,
    const float* __restrict__ bias,
    const int* __restrict__ label_index,
    const int* __restrict__ scope,
    const float* __restrict__ cls,
    float* __restrict__ out)
{
    __shared__ __align__(16) float part[4][464];   // per-wave weighted-sum partials
    __shared__ float zs[4][4];                     // per-wave z0,z1,sv0,sv1
    __shared__ __align__(16) float t01[464];       // tower (t0 | t1)

    int b = blockIdx.x;
    int start = scope[b];
    int cnt = scope[b + 1] - start;   // 48 for this problem
    int tid = threadIdx.x;
    int wave = tid >> 6;
    int lane = tid & 63;
    const float* xb = x + (long long)start * H;

    // w_s slices hoisted to registers as float2 (zero past H).
    const float2* w0p = (const float2*)w_s;          // 115 float2
    const float2* w1p = (const float2*)(w_s + H3);   // 690 % 2 == 0, aligned
    float2 w0a = w0p[lane];
    float2 w1a = w1p[lane];
    float2 w0b = make_float2(0.f, 0.f), w1b = make_float2(0.f, 0.f);
    if (lane < 51) { w0b = w0p[64 + lane]; w1b = w1p[64 + lane]; }

    float2 acc0[2] = { make_float2(0.f, 0.f), make_float2(0.f, 0.f) };
    float2 acc1[2] = { make_float2(0.f, 0.f), make_float2(0.f, 0.f) };
    float z0 = 0.f, z1 = 0.f, sv0 = 0.f, sv1 = 0.f;

    auto load_row = [&](int i, float2& a, float2& bb, int& c) {
        const float2* row2 = (const float2*)(xb + i * H);
        a = row2[lane];                                         // j = 2*lane
        bb = (lane < 51) ? row2[64 + lane] : make_float2(0.f, 0.f); // j = 128+2*lane
        c = label_index[start + i];                             // wave-uniform
    };

    auto body = [&](float2 a, float2 bb, int c) {
        float t0 = fast_tanh(a.x);
        float t1 = fast_tanh(a.y);
        float t2 = fast_tanh(bb.x);   // lanes>=51: bb==0 -> tanh(0)==0
        float t3 = fast_tanh(bb.y);
        float d0 = w0a.x * t0 + w0a.y * t1 + w0b.x * t2 + w0b.y * t3;
        float d1 = w1a.x * t0 + w1a.y * t1 + w1b.x * t2 + w1b.y * t3;
        // allreduce (xor butterfly broadcasts the sum to all lanes)
#pragma unroll
        for (int m = 32; m; m >>= 1) {
            d0 += __shfl_xor(d0, m);
            d1 += __shfl_xor(d1, m);
        }
        float e0 = __expf(d0 + cls[c]);
        float e1 = __expf(d1 + cls[NC + c]);
        z0 += e0; z1 += e1;
        sv0 += cls[2 * NC + c];
        sv1 += cls[3 * NC + c];
        acc0[0].x = fmaf(e0, a.x,  acc0[0].x);
        acc0[0].y = fmaf(e0, a.y,  acc0[0].y);
        acc0[1].x = fmaf(e0, bb.x, acc0[1].x);
        acc0[1].y = fmaf(e0, bb.y, acc0[1].y);
        acc1[0].x = fmaf(e1, a.x,  acc1[0].x);
        acc1[0].y = fmaf(e1, a.y,  acc1[0].y);
        acc1[1].x = fmaf(e1, bb.x, acc1[1].x);
        acc1[1].y = fmaf(e1, bb.y, acc1[1].y);
    };

    if (cnt == 48) {
        // Fully unrolled, 2-deep rotating software pipeline. Wave w owns
        // instances w, w+4, ..., w+44 (12 of them).
        float2 a0, b0, a1, b1;
        float2 a2 = make_float2(0.f, 0.f), b2 = make_float2(0.f, 0.f);
        int c0, c1, c2 = 0;
        load_row(wave,     a0, b0, c0);
        load_row(wave + 4, a1, b1, c1);
#pragma unroll
        for (int t = 0; t < 12; ++t) {
            if (t + 2 < 12) load_row(wave + 4 * (t + 2), a2, b2, c2);
            body(a0, b0, c0);
            a0 = a1; b0 = b1; c0 = c1;
            a1 = a2; b1 = b2; c1 = c2;
        }
    } else {
        for (int i = wave; i < cnt; i += 4) {
            float2 a, bb; int c;
            load_row(i, a, bb, c);
            body(a, bb, c);
        }
    }

    // ---- Cross-wave merge through LDS (float2 stores, 2-way = free).
    float2* pw = (float2*)part[wave];
    pw[lane]       = acc0[0];            // floats [0,128)
    pw[115 + lane] = acc1[0];            // floats [230,358)
    if (lane < 51) {
        pw[64 + lane]        = acc0[1];  // floats [128,230)
        pw[115 + 64 + lane]  = acc1[1];  // floats [358,460)
    }
    if (lane == 0) {
        zs[wave][0] = z0; zs[wave][1] = z1;
        zs[wave][2] = sv0; zs[wave][3] = sv1;
    }
    __syncthreads();

    float zt0 = zs[0][0] + zs[1][0] + zs[2][0] + zs[3][0];
    float zt1 = zs[0][1] + zs[1][1] + zs[2][1] + zs[3][1];
    float st0 = zs[0][2] + zs[1][2] + zs[2][2] + zs[3][2];
    float st1 = zs[0][3] + zs[1][3] + zs[2][3] + zs[3][3];
    float rc  = __builtin_amdgcn_rcpf((float)cnt);
    float s0  = st0 * rc * __builtin_amdgcn_rcpf(zt0);  // layer_att0 / z0
    float s1  = st1 * rc * __builtin_amdgcn_rcpf(zt1);  // layer_att1 / z1

    for (int t = tid; t < 2 * H; t += 256) {
        float s = part[0][t] + part[1][t] + part[2][t] + part[3][t];
        t01[t] = s * (t < H ? s0 : s1);
    }
    __syncthreads();

    // ---- Output projection, float4 both sides. 4 threads per class.
    int q = tid & 3;
    int c = tid >> 2;
    if (c < NC) {
        const float4* drow4 = (const float4*)(disc + c * (2 * H)); // 460 floats = 115 float4
        const float4* t4 = (const float4*)t01;
        float acc = 0.f;
        for (int k = q; k < 115; k += 4) {
            float4 dv = drow4[k];
            float4 tv = t4[k];
            acc += dv.x * tv.x + dv.y * tv.y + dv.z * tv.z + dv.w * tv.w;
        }
        acc += __shfl_down(acc, 2, 4);
        acc += __shfl_down(acc, 1, 4);
        if (q == 0) out[b * NC + c] = acc + bias[c];
    }
}

extern "C" void kernel_launch(void* const* d_in, const int* in_sizes, int n_in,
                              void* d_out, int out_size, void* d_ws, size_t ws_size,
                              hipStream_t stream) {
    const float* x               = (const float*)d_in[0];
    const float* rel_emb0        = (const float*)d_in[1];
    const float* rel_emb1        = (const float*)d_in[2];
    const float* att_w0          = (const float*)d_in[3];
    const float* att_w1          = (const float*)d_in[4];
    const float* w_s             = (const float*)d_in[5];
    const float* b_s             = (const float*)d_in[6];
    const float* disc            = (const float*)d_in[7];
    const float* bias            = (const float*)d_in[8];
    const int*   label_index     = (const int*)d_in[9];
    const int*   relation_levels = (const int*)d_in[10];
    const int*   scope           = (const int*)d_in[11];
    float* out = (float*)d_out;
    float* cls = (float*)d_ws;   // 4*NC floats

    class_table_kernel<<<NC, 64, 0, stream>>>(rel_emb0, rel_emb1, att_w0, att_w1,
                                              w_s, b_s, relation_levels, cls);
    bag_kernel<<<BAGS, 256, 0, stream>>>(x, w_s, disc, bias, label_index, scope,
                                         cls, out);
}

// Round 2
// 359.277 us; speedup vs baseline: 1.1145x; 1.1145x over previous
//
#include <hip/hip_runtime.h>

#define NTOT 196608
#define BAGS 4096
#define H 230
#define H3 690
#define NC 53

// tanh(x) = 1 - 2/(exp(2x)+1), v_rcp instead of precise division.
// Saturates correctly at +/-1 for large |x|.
__device__ __forceinline__ float fast_tanh(float x) {
    float e = __expf(2.f * x);
    float r = __builtin_amdgcn_rcpf(e + 1.f);
    return fmaf(-2.f, r, 1.f);
}

// ---------------------------------------------------------------------------
// Kernel 0: per-class table (53 classes).
// cls[0*NC+c] = logit const k=0, cls[1*NC+c] = logit const k=1,
// cls[2*NC+c] = vsm0, cls[3*NC+c] = vsm1
// ---------------------------------------------------------------------------
__global__ void class_table_kernel(const float* __restrict__ rel_emb0,
                                   const float* __restrict__ rel_emb1,
                                   const float* __restrict__ att_w0,
                                   const float* __restrict__ att_w1,
                                   const float* __restrict__ w_s,
                                   const float* __restrict__ b_s,
                                   const int* __restrict__ relation_levels,
                                   float* __restrict__ cls)
{
    int c = blockIdx.x;
    int lane = threadIdx.x;  // 64 threads
    int l0 = relation_levels[c * 2 + 0];
    int l1 = relation_levels[c * 2 + 1];
    float a00 = 0.f, a01 = 0.f, a10 = 0.f, a11 = 0.f;
    for (int j = lane; j < H; j += 64) {
        float t0 = fast_tanh(rel_emb0[l0 * H + j]);
        float t1 = fast_tanh(rel_emb1[l1 * H + j]);
        a00 += w_s[0 * H3 + H + j] * t0;
        a01 += w_s[0 * H3 + 2 * H + j] * t1;
        a10 += w_s[1 * H3 + H + j] * t0;
        a11 += w_s[1 * H3 + 2 * H + j] * t1;
    }
    for (int m = 32; m; m >>= 1) {
        a00 += __shfl_xor(a00, m);
        a01 += __shfl_xor(a01, m);
        a10 += __shfl_xor(a10, m);
        a11 += __shfl_xor(a11, m);
    }
    if (lane == 0) {
        cls[0 * NC + c] = a00 + a01 + b_s[0];
        cls[1 * NC + c] = a10 + a11 + b_s[1];
        float v0 = att_w0[l0], v1 = att_w1[l1];
        float mx = fmaxf(v0, v1);
        float e0 = __expf(v0 - mx), e1 = __expf(v1 - mx);
        float rz = __builtin_amdgcn_rcpf(e0 + e1);
        cls[2 * NC + c] = e0 * rz;
        cls[3 * NC + c] = e1 * rz;
    }
}

// ---------------------------------------------------------------------------
// Kernel 1: one block per bag, SINGLE pass over x.
// FLAT code only — round-1's lambdas were outlined by the compiler and all
// loop state went to scratch (WRITE_SIZE 300 MB, VGPR 40, 2.4x regression).
// cnt==48 fast path processes TWO instances per iteration: the 12-step
// serial butterfly is the latency bottleneck; 4 independent chains
// (d0/d1 x 2 instances) interleave for 2x ILP. float2 loads (rows are
// 8B-aligned: 920 % 8 == 0). __launch_bounds__(256,8): 64 VGPR is enough
// (compiler used only 40 last round), 8 blocks/CU.
// Lane mapping: a -> elements 2*lane, 2*lane+1 (j in [0,128));
//               b -> elements 128+2*lane (lane<51, j in [128,230)).
// ---------------------------------------------------------------------------
__global__ __launch_bounds__(256, 8) void bag_kernel(
    const float* __restrict__ x,
    const float* __restrict__ w_s,
    const float* __restrict__ disc,
    const float* __restrict__ bias,
    const int* __restrict__ label_index,
    const int* __restrict__ scope,
    const float* __restrict__ cls,
    float* __restrict__ out)
{
    __shared__ __align__(16) float part[4][464];   // per-wave weighted-sum partials
    __shared__ float zs[4][4];                     // per-wave z0,z1,sv0,sv1
    __shared__ __align__(16) float t01[464];       // tower (t0 | t1)

    int b = blockIdx.x;
    int start = scope[b];
    int cnt = scope[b + 1] - start;   // 48 for this problem
    int tid = threadIdx.x;
    int wave = tid >> 6;
    int lane = tid & 63;
    const float* xb = x + (long long)start * H;

    // w_s slices hoisted to registers as float2 (zero past H).
    const float2* w0p = (const float2*)w_s;          // 115 float2
    const float2* w1p = (const float2*)(w_s + H3);   // 690 % 2 == 0, aligned
    float2 w0a = w0p[lane];
    float2 w1a = w1p[lane];
    float2 w0b = make_float2(0.f, 0.f), w1b = make_float2(0.f, 0.f);
    if (lane < 51) { w0b = w0p[64 + lane]; w1b = w1p[64 + lane]; }

    float2 acc0a = make_float2(0.f, 0.f), acc0b = make_float2(0.f, 0.f);
    float2 acc1a = make_float2(0.f, 0.f), acc1b = make_float2(0.f, 0.f);
    float z0 = 0.f, z1 = 0.f, sv0 = 0.f, sv1 = 0.f;

    if (cnt == 48) {
        // Wave w owns instances w, w+4, ..., w+44. Pairs: (w+8t, w+8t+4).
#pragma unroll
        for (int tt = 0; tt < 6; ++tt) {
            int iA = wave + 8 * tt;
            int iB = iA + 4;
            const float2* rA = (const float2*)(xb + iA * H);
            const float2* rB = (const float2*)(xb + iB * H);
            float2 aA = rA[lane];
            float2 aB = rB[lane];
            float2 bA = make_float2(0.f, 0.f), bB = make_float2(0.f, 0.f);
            if (lane < 51) { bA = rA[64 + lane]; bB = rB[64 + lane]; }
            int cA = __builtin_amdgcn_readfirstlane(label_index[start + iA]);
            int cB = __builtin_amdgcn_readfirstlane(label_index[start + iB]);

            float tA0 = fast_tanh(aA.x), tA1 = fast_tanh(aA.y);
            float tA2 = fast_tanh(bA.x), tA3 = fast_tanh(bA.y);
            float tB0 = fast_tanh(aB.x), tB1 = fast_tanh(aB.y);
            float tB2 = fast_tanh(bB.x), tB3 = fast_tanh(bB.y);

            float d0A = w0a.x * tA0 + w0a.y * tA1 + w0b.x * tA2 + w0b.y * tA3;
            float d1A = w1a.x * tA0 + w1a.y * tA1 + w1b.x * tA2 + w1b.y * tA3;
            float d0B = w0a.x * tB0 + w0a.y * tB1 + w0b.x * tB2 + w0b.y * tB3;
            float d1B = w1a.x * tB0 + w1a.y * tB1 + w1b.x * tB2 + w1b.y * tB3;

            // 4 independent butterfly chains interleave in the issue slots.
#pragma unroll
            for (int m = 32; m; m >>= 1) {
                d0A += __shfl_xor(d0A, m);
                d1A += __shfl_xor(d1A, m);
                d0B += __shfl_xor(d0B, m);
                d1B += __shfl_xor(d1B, m);
            }

            float e0A = __expf(d0A + cls[cA]);
            float e1A = __expf(d1A + cls[NC + cA]);
            float e0B = __expf(d0B + cls[cB]);
            float e1B = __expf(d1B + cls[NC + cB]);
            z0 += e0A + e0B;
            z1 += e1A + e1B;
            sv0 += cls[2 * NC + cA] + cls[2 * NC + cB];
            sv1 += cls[3 * NC + cA] + cls[3 * NC + cB];

            acc0a.x = fmaf(e0A, aA.x, acc0a.x); acc0a.y = fmaf(e0A, aA.y, acc0a.y);
            acc0b.x = fmaf(e0A, bA.x, acc0b.x); acc0b.y = fmaf(e0A, bA.y, acc0b.y);
            acc1a.x = fmaf(e1A, aA.x, acc1a.x); acc1a.y = fmaf(e1A, aA.y, acc1a.y);
            acc1b.x = fmaf(e1A, bA.x, acc1b.x); acc1b.y = fmaf(e1A, bA.y, acc1b.y);
            acc0a.x = fmaf(e0B, aB.x, acc0a.x); acc0a.y = fmaf(e0B, aB.y, acc0a.y);
            acc0b.x = fmaf(e0B, bB.x, acc0b.x); acc0b.y = fmaf(e0B, bB.y, acc0b.y);
            acc1a.x = fmaf(e1B, aB.x, acc1a.x); acc1a.y = fmaf(e1B, aB.y, acc1a.y);
            acc1b.x = fmaf(e1B, bB.x, acc1b.x); acc1b.y = fmaf(e1B, bB.y, acc1b.y);
        }
    } else {
        for (int i = wave; i < cnt; i += 4) {
            const float2* rA = (const float2*)(xb + i * H);
            float2 aA = rA[lane];
            float2 bA = make_float2(0.f, 0.f);
            if (lane < 51) bA = rA[64 + lane];
            int cA = __builtin_amdgcn_readfirstlane(label_index[start + i]);

            float tA0 = fast_tanh(aA.x), tA1 = fast_tanh(aA.y);
            float tA2 = fast_tanh(bA.x), tA3 = fast_tanh(bA.y);
            float d0A = w0a.x * tA0 + w0a.y * tA1 + w0b.x * tA2 + w0b.y * tA3;
            float d1A = w1a.x * tA0 + w1a.y * tA1 + w1b.x * tA2 + w1b.y * tA3;
#pragma unroll
            for (int m = 32; m; m >>= 1) {
                d0A += __shfl_xor(d0A, m);
                d1A += __shfl_xor(d1A, m);
            }
            float e0A = __expf(d0A + cls[cA]);
            float e1A = __expf(d1A + cls[NC + cA]);
            z0 += e0A; z1 += e1A;
            sv0 += cls[2 * NC + cA];
            sv1 += cls[3 * NC + cA];
            acc0a.x = fmaf(e0A, aA.x, acc0a.x); acc0a.y = fmaf(e0A, aA.y, acc0a.y);
            acc0b.x = fmaf(e0A, bA.x, acc0b.x); acc0b.y = fmaf(e0A, bA.y, acc0b.y);
            acc1a.x = fmaf(e1A, aA.x, acc1a.x); acc1a.y = fmaf(e1A, aA.y, acc1a.y);
            acc1b.x = fmaf(e1A, bA.x, acc1b.x); acc1b.y = fmaf(e1A, bA.y, acc1b.y);
        }
    }

    // ---- Cross-wave merge through LDS (float2 stores, 2-way = free).
    float2* pw = (float2*)part[wave];
    pw[lane]       = acc0a;              // floats [0,128)
    pw[115 + lane] = acc1a;              // floats [230,358)
    if (lane < 51) {
        pw[64 + lane]       = acc0b;     // floats [128,230)
        pw[115 + 64 + lane] = acc1b;     // floats [358,460)
    }
    if (lane == 0) {
        zs[wave][0] = z0; zs[wave][1] = z1;
        zs[wave][2] = sv0; zs[wave][3] = sv1;
    }
    __syncthreads();

    float zt0 = zs[0][0] + zs[1][0] + zs[2][0] + zs[3][0];
    float zt1 = zs[0][1] + zs[1][1] + zs[2][1] + zs[3][1];
    float st0 = zs[0][2] + zs[1][2] + zs[2][2] + zs[3][2];
    float st1 = zs[0][3] + zs[1][3] + zs[2][3] + zs[3][3];
    float rc  = __builtin_amdgcn_rcpf((float)cnt);
    float s0  = st0 * rc * __builtin_amdgcn_rcpf(zt0);  // layer_att0 / z0
    float s1  = st1 * rc * __builtin_amdgcn_rcpf(zt1);  // layer_att1 / z1

    for (int t = tid; t < 2 * H; t += 256) {
        float s = part[0][t] + part[1][t] + part[2][t] + part[3][t];
        t01[t] = s * (t < H ? s0 : s1);
    }
    __syncthreads();

    // ---- Output projection, float4 both sides. 4 threads per class.
    int q = tid & 3;
    int c = tid >> 2;
    if (c < NC) {
        const float4* drow4 = (const float4*)(disc + c * (2 * H)); // 460 floats = 115 float4
        const float4* t4 = (const float4*)t01;
        float acc = 0.f;
        for (int k = q; k < 115; k += 4) {
            float4 dv = drow4[k];
            float4 tv = t4[k];
            acc += dv.x * tv.x + dv.y * tv.y + dv.z * tv.z + dv.w * tv.w;
        }
        acc += __shfl_down(acc, 2, 4);
        acc += __shfl_down(acc, 1, 4);
        if (q == 0) out[b * NC + c] = acc + bias[c];
    }
}

extern "C" void kernel_launch(void* const* d_in, const int* in_sizes, int n_in,
                              void* d_out, int out_size, void* d_ws, size_t ws_size,
                              hipStream_t stream) {
    const float* x               = (const float*)d_in[0];
    const float* rel_emb0        = (const float*)d_in[1];
    const float* rel_emb1        = (const float*)d_in[2];
    const float* att_w0          = (const float*)d_in[3];
    const float* att_w1          = (const float*)d_in[4];
    const float* w_s             = (const float*)d_in[5];
    const float* b_s             = (const float*)d_in[6];
    const float* disc            = (const float*)d_in[7];
    const float* bias            = (const float*)d_in[8];
    const int*   label_index     = (const int*)d_in[9];
    const int*   relation_levels = (const int*)d_in[10];
    const int*   scope           = (const int*)d_in[11];
    float* out = (float*)d_out;
    float* cls = (float*)d_ws;   // 4*NC floats

    class_table_kernel<<<NC, 64, 0, stream>>>(rel_emb0, rel_emb1, att_w0, att_w1,
                                              w_s, b_s, relation_levels, cls);
    bag_kernel<<<BAGS, 256, 0, stream>>>(x, w_s, disc, bias, label_index, scope,
                                         cls, out);
}

// Round 3
// 322.409 us; speedup vs baseline: 1.2419x; 1.1144x over previous
//
#include <hip/hip_runtime.h>

#define NTOT 196608
#define BAGS 4096
#define H 230
#define H3 690
#define NC 53
#define RMAX 48          // rows per LDS chunk
#define STR 65           // padded lane-stride for dp rows (65 mod 32 = 1 -> conflict-free)

// tanh(x) = 1 - 2/(exp(2x)+1), v_rcp instead of precise division.
__device__ __forceinline__ float fast_tanh(float x) {
    float e = __expf(2.f * x);
    float r = __builtin_amdgcn_rcpf(e + 1.f);
    return fmaf(-2.f, r, 1.f);
}

// ---------------------------------------------------------------------------
// Kernel 0: per-class table (53 classes).
// cls[0*NC+c] = logit const k=0, cls[1*NC+c] = logit const k=1,
// cls[2*NC+c] = vsm0, cls[3*NC+c] = vsm1
// ---------------------------------------------------------------------------
__global__ void class_table_kernel(const float* __restrict__ rel_emb0,
                                   const float* __restrict__ rel_emb1,
                                   const float* __restrict__ att_w0,
                                   const float* __restrict__ att_w1,
                                   const float* __restrict__ w_s,
                                   const float* __restrict__ b_s,
                                   const int* __restrict__ relation_levels,
                                   float* __restrict__ cls)
{
    int c = blockIdx.x;
    int lane = threadIdx.x;  // 64 threads
    int l0 = relation_levels[c * 2 + 0];
    int l1 = relation_levels[c * 2 + 1];
    float a00 = 0.f, a01 = 0.f, a10 = 0.f, a11 = 0.f;
    for (int j = lane; j < H; j += 64) {
        float t0 = fast_tanh(rel_emb0[l0 * H + j]);
        float t1 = fast_tanh(rel_emb1[l1 * H + j]);
        a00 += w_s[0 * H3 + H + j] * t0;
        a01 += w_s[0 * H3 + 2 * H + j] * t1;
        a10 += w_s[1 * H3 + H + j] * t0;
        a11 += w_s[1 * H3 + 2 * H + j] * t1;
    }
    for (int m = 32; m; m >>= 1) {
        a00 += __shfl_xor(a00, m);
        a01 += __shfl_xor(a01, m);
        a10 += __shfl_xor(a10, m);
        a11 += __shfl_xor(a11, m);
    }
    if (lane == 0) {
        cls[0 * NC + c] = a00 + a01 + b_s[0];
        cls[1 * NC + c] = a10 + a11 + b_s[1];
        float v0 = att_w0[l0], v1 = att_w1[l1];
        float mx = fmaxf(v0, v1);
        float e0 = __expf(v0 - mx), e1 = __expf(v1 - mx);
        float rz = __builtin_amdgcn_rcpf(e0 + e1);
        cls[2 * NC + c] = e0 * rz;
        cls[3 * NC + c] = e1 * rz;
    }
}

// ---------------------------------------------------------------------------
// Kernel 1: one block per bag. THREE-PHASE structure — no serial per-row
// reduce chain, no long-lived state across latency (rounds 1-2 spilled:
// WRITE_SIZE 226-300 MB of scratch; this design needs ~45 VGPRs, no spill).
//  P1: stream rows once (HBM), per-lane dot partials -> LDS dp0/dp1.
//  P2: waves 0/2, lane=row: sum 64 partials, exp -> e[row] in LDS; butterfly
//      once per wave for z/sv totals.
//  P3: re-read rows (L2/L3-hot, no extra HBM fetch), fma with broadcast e.
// dp buffer is overlaid by part/t01 in the epilogue (barrier-ordered).
// LDS 25.4 KB -> 6 blocks/CU at __launch_bounds__(256,6).
// Lane map: a -> elems 2l,2l+1 (j<128); b -> 128+2l,129+2l (l<51).
// ---------------------------------------------------------------------------
__global__ __launch_bounds__(256, 6) void bag_kernel(
    const float* __restrict__ x,
    const float* __restrict__ w_s,
    const float* __restrict__ disc,
    const float* __restrict__ bias,
    const int* __restrict__ label_index,
    const int* __restrict__ scope,
    const float* __restrict__ cls,
    float* __restrict__ out)
{
    // smem layout (floats):
    //   dp0 = smem[0 .. RMAX*STR)          = [0, 3120)
    //   dp1 = smem[3120 .. 6240)
    //   epilogue overlay: part[4][464] = smem[0,1856), t01 = smem[1856,2320)
    __shared__ __align__(16) float smem[2 * RMAX * STR];
    __shared__ __align__(16) float eArr[2 * RMAX];
    __shared__ float zsv[4];   // z0, sv0, z1, sv1

    int b = blockIdx.x;
    int start = scope[b];
    int cnt = scope[b + 1] - start;   // 48 for this problem
    int tid = threadIdx.x;
    int wave = tid >> 6;
    int lane = tid & 63;
    const float* xb = x + (long long)start * H;

    // w_s slices hoisted to registers as float2 (zero past H).
    const float2* w0p = (const float2*)w_s;          // 115 float2
    const float2* w1p = (const float2*)(w_s + H3);   // 690 % 2 == 0, aligned
    float2 w0a = w0p[lane];
    float2 w1a = w1p[lane];
    float2 w0b = make_float2(0.f, 0.f), w1b = make_float2(0.f, 0.f);
    if (lane < 51) { w0b = w0p[64 + lane]; w1b = w1p[64 + lane]; }

    float2 acc0a = make_float2(0.f, 0.f), acc0b = make_float2(0.f, 0.f);
    float2 acc1a = make_float2(0.f, 0.f), acc1b = make_float2(0.f, 0.f);

    float* dp0 = smem;
    float* dp1 = smem + RMAX * STR;

    for (int cb = 0; cb < cnt; cb += RMAX) {
        int ce = cb + RMAX; if (ce > cnt) ce = cnt;
        int rows = ce - cb;

        // ---- Phase 1: stream rows, per-lane dot partials -> LDS. No
        // loop-carried deps; body = 2 loads, 4 tanh, 8 fma, 2 ds_write.
        for (int i = cb + wave; i < ce; i += 4) {
            const float2* r2 = (const float2*)(xb + (long long)i * H);
            float2 a = r2[lane];
            float2 bb = make_float2(0.f, 0.f);
            if (lane < 51) bb = r2[64 + lane];
            float t0 = fast_tanh(a.x), t1 = fast_tanh(a.y);
            float t2 = fast_tanh(bb.x), t3 = fast_tanh(bb.y);
            int ir = i - cb;
            dp0[ir * STR + lane] = w0a.x * t0 + w0a.y * t1 + w0b.x * t2 + w0b.y * t3;
            dp1[ir * STR + lane] = w1a.x * t0 + w1a.y * t1 + w1b.x * t2 + w1b.y * t3;
        }
        __syncthreads();

        // ---- Phase 2: waves 0 (d0) and 2 (d1), lane = row.
        if ((wave & 1) == 0) {
            int g = wave >> 1;               // 0 -> logit k=0, 1 -> k=1
            float zp = 0.f, svp = 0.f;
            if (lane < rows) {
                const float* dpr = (g ? dp1 : dp0) + lane * STR;
                float s = 0.f;
#pragma unroll
                for (int l = 0; l < 64; ++l) s += dpr[l];
                int c = label_index[start + cb + lane];
                float e = __expf(s + cls[g * NC + c]);
                eArr[2 * lane + g] = e;
                zp = e;
                svp = cls[(2 + g) * NC + c];
            }
#pragma unroll
            for (int m = 32; m; m >>= 1) {
                zp  += __shfl_xor(zp, m);
                svp += __shfl_xor(svp, m);
            }
            if (lane == 0) {
                if (cb == 0) { zsv[2 * g] = zp;  zsv[2 * g + 1] = svp; }
                else         { zsv[2 * g] += zp; zsv[2 * g + 1] += svp; }
            }
        }
        __syncthreads();

        // ---- Phase 3: re-read rows (L2/L3-hot), weighted accumulate.
        for (int i = cb + wave; i < ce; i += 4) {
            const float2* r2 = (const float2*)(xb + (long long)i * H);
            float2 a = r2[lane];
            float2 bb = make_float2(0.f, 0.f);
            if (lane < 51) bb = r2[64 + lane];
            int ir = i - cb;
            float e0 = eArr[2 * ir];       // uniform addr -> LDS broadcast
            float e1 = eArr[2 * ir + 1];
            acc0a.x = fmaf(e0, a.x,  acc0a.x); acc0a.y = fmaf(e0, a.y,  acc0a.y);
            acc0b.x = fmaf(e0, bb.x, acc0b.x); acc0b.y = fmaf(e0, bb.y, acc0b.y);
            acc1a.x = fmaf(e1, a.x,  acc1a.x); acc1a.y = fmaf(e1, a.y,  acc1a.y);
            acc1b.x = fmaf(e1, bb.x, acc1b.x); acc1b.y = fmaf(e1, bb.y, acc1b.y);
        }
        // No sync needed before next chunk's phase 1: dp writes were ordered
        // by the sync after phase 2; phase 3 touches only eArr + global.
    }

    // ---- Cross-wave merge. part[4][464] overlays dp0 (all dp reads are
    // behind the phase-2 sync of the last chunk).
    float2* pw = (float2*)(smem + wave * 464);
    pw[lane]       = acc0a;              // floats [0,128)
    pw[115 + lane] = acc1a;              // floats [230,358)
    if (lane < 51) {
        pw[64 + lane]       = acc0b;     // floats [128,230)
        pw[115 + 64 + lane] = acc1b;     // floats [358,460)
    }
    __syncthreads();

    float rc = __builtin_amdgcn_rcpf((float)cnt);
    float s0 = zsv[1] * rc * __builtin_amdgcn_rcpf(zsv[0]);  // sv0/(cnt*z0)
    float s1 = zsv[3] * rc * __builtin_amdgcn_rcpf(zsv[2]);  // sv1/(cnt*z1)

    float* t01 = smem + 1856;
    for (int t = tid; t < 2 * H; t += 256) {
        float s = smem[t] + smem[464 + t] + smem[928 + t] + smem[1392 + t];
        t01[t] = s * (t < H ? s0 : s1);
    }
    __syncthreads();

    // ---- Output projection, float4 both sides. 4 threads per class.
    int q = tid & 3;
    int c = tid >> 2;
    if (c < NC) {
        const float4* drow4 = (const float4*)(disc + c * (2 * H)); // 115 float4
        const float4* t4 = (const float4*)t01;
        float acc = 0.f;
        for (int k = q; k < 115; k += 4) {
            float4 dv = drow4[k];
            float4 tv = t4[k];
            acc += dv.x * tv.x + dv.y * tv.y + dv.z * tv.z + dv.w * tv.w;
        }
        acc += __shfl_down(acc, 2, 4);
        acc += __shfl_down(acc, 1, 4);
        if (q == 0) out[b * NC + c] = acc + bias[c];
    }
}

extern "C" void kernel_launch(void* const* d_in, const int* in_sizes, int n_in,
                              void* d_out, int out_size, void* d_ws, size_t ws_size,
                              hipStream_t stream) {
    const float* x               = (const float*)d_in[0];
    const float* rel_emb0        = (const float*)d_in[1];
    const float* rel_emb1        = (const float*)d_in[2];
    const float* att_w0          = (const float*)d_in[3];
    const float* att_w1          = (const float*)d_in[4];
    const float* w_s             = (const float*)d_in[5];
    const float* b_s             = (const float*)d_in[6];
    const float* disc            = (const float*)d_in[7];
    const float* bias            = (const float*)d_in[8];
    const int*   label_index     = (const int*)d_in[9];
    const int*   relation_levels = (const int*)d_in[10];
    const int*   scope           = (const int*)d_in[11];
    float* out = (float*)d_out;
    float* cls = (float*)d_ws;   // 4*NC floats

    class_table_kernel<<<NC, 64, 0, stream>>>(rel_emb0, rel_emb1, att_w0, att_w1,
                                              w_s, b_s, relation_levels, cls);
    bag_kernel<<<BAGS, 256, 0, stream>>>(x, w_s, disc, bias, label_index, scope,
                                         cls, out);
}

// Round 4
// 303.338 us; speedup vs baseline: 1.3200x; 1.0629x over previous
//
#include <hip/hip_runtime.h>

#define NTOT 196608
#define BAGS 4096
#define H 230
#define H3 690
#define NC 53

// tanh(x) = 1 - 2/(exp(2x)+1), v_rcp instead of precise division.
__device__ __forceinline__ float fast_tanh(float x) {
    float e = __expf(2.f * x);
    float r = __builtin_amdgcn_rcpf(e + 1.f);
    return fmaf(-2.f, r, 1.f);
}

// ---------------------------------------------------------------------------
// Kernel 0: per-class table (53 classes).
// cls[0*NC+c] = logit const k=0, cls[1*NC+c] = logit const k=1,
// cls[2*NC+c] = vsm0, cls[3*NC+c] = vsm1
// ---------------------------------------------------------------------------
__global__ void class_table_kernel(const float* __restrict__ rel_emb0,
                                   const float* __restrict__ rel_emb1,
                                   const float* __restrict__ att_w0,
                                   const float* __restrict__ att_w1,
                                   const float* __restrict__ w_s,
                                   const float* __restrict__ b_s,
                                   const int* __restrict__ relation_levels,
                                   float* __restrict__ cls)
{
    int c = blockIdx.x;
    int lane = threadIdx.x;  // 64 threads
    int l0 = relation_levels[c * 2 + 0];
    int l1 = relation_levels[c * 2 + 1];
    float a00 = 0.f, a01 = 0.f, a10 = 0.f, a11 = 0.f;
    for (int j = lane; j < H; j += 64) {
        float t0 = fast_tanh(rel_emb0[l0 * H + j]);
        float t1 = fast_tanh(rel_emb1[l1 * H + j]);
        a00 += w_s[0 * H3 + H + j] * t0;
        a01 += w_s[0 * H3 + 2 * H + j] * t1;
        a10 += w_s[1 * H3 + H + j] * t0;
        a11 += w_s[1 * H3 + 2 * H + j] * t1;
    }
    for (int m = 32; m; m >>= 1) {
        a00 += __shfl_xor(a00, m);
        a01 += __shfl_xor(a01, m);
        a10 += __shfl_xor(a10, m);
        a11 += __shfl_xor(a11, m);
    }
    if (lane == 0) {
        cls[0 * NC + c] = a00 + a01 + b_s[0];
        cls[1 * NC + c] = a10 + a11 + b_s[1];
        float v0 = att_w0[l0], v1 = att_w1[l1];
        float mx = fmaxf(v0, v1);
        float e0 = __expf(v0 - mx), e1 = __expf(v1 - mx);
        float rz = __builtin_amdgcn_rcpf(e0 + e1);
        cls[2 * NC + c] = e0 * rz;
        cls[3 * NC + c] = e1 * rz;
    }
}

// ---------------------------------------------------------------------------
// Kernel 1: one block per bag, SINGLE pass over x, rows held in REGISTERS.
// Lessons encoded:
//  * R1/R2: live-state > launch_bounds cap => allocator collapses to scratch
//    (WRITE_SIZE 226-300 MB). Fix: (256,4) => 128-VGPR cap, demand ~100.
//  * R3: LDS round-trip + 2 barriers/chunk + half-idle P2 = latency-bound
//    (VALUBusy 24%, HBM 18%). Fix: no mid-loop barriers, no dp LDS.
//  * VALU work ~28us == HBM floor ~29us => must overlap; all 24 row loads
//    issue up-front per wave (deep MLP), butterflies run 8 chains interleaved.
// Fast path cnt==48: wave w owns rows w+4t, t=0..11, all in registers.
// WRITE_SIZE is the spill tripwire: must stay ~1 MB.
// ---------------------------------------------------------------------------
__global__ __launch_bounds__(256, 4) void bag_kernel(
    const float* __restrict__ x,
    const float* __restrict__ w_s,
    const float* __restrict__ disc,
    const float* __restrict__ bias,
    const int* __restrict__ label_index,
    const int* __restrict__ scope,
    const float* __restrict__ cls,
    float* __restrict__ out)
{
    __shared__ __align__(16) float part[4][464];   // per-wave weighted-sum partials
    __shared__ float zs[4][4];                     // per-wave z0,z1,sv0,sv1
    __shared__ __align__(16) float t01[464];       // tower (t0 | t1)

    int b = blockIdx.x;
    int start = scope[b];
    int cnt = scope[b + 1] - start;   // 48 for this problem
    int tid = threadIdx.x;
    int wave = tid >> 6;
    int lane = tid & 63;
    const float* xb = x + (long long)start * H;

    // w_s slices hoisted to registers as float2 (zero past H).
    const float2* w0p = (const float2*)w_s;          // 115 float2
    const float2* w1p = (const float2*)(w_s + H3);   // 690 % 2 == 0, aligned
    float2 w0a = w0p[lane];
    float2 w1a = w1p[lane];
    float2 w0b = make_float2(0.f, 0.f), w1b = make_float2(0.f, 0.f);
    if (lane < 51) { w0b = w0p[64 + lane]; w1b = w1p[64 + lane]; }

    float2 acc0a = make_float2(0.f, 0.f), acc0b = make_float2(0.f, 0.f);
    float2 acc1a = make_float2(0.f, 0.f), acc1b = make_float2(0.f, 0.f);
    float z0 = 0.f, z1 = 0.f, sv0 = 0.f, sv1 = 0.f;

    if (cnt == 48) {
        // Labels first (wave-uniform scalar loads, tiny, L2-hot).
        int cl[12];
#pragma unroll
        for (int t = 0; t < 12; ++t)
            cl[t] = label_index[start + wave + 4 * t];

        // All 24 row loads issued up-front: 12 rows x 2 float2 per lane.
        float2 ra[12], rb[12];
#pragma unroll
        for (int t = 0; t < 12; ++t) {
            const float2* r2 = (const float2*)(xb + (wave + 4 * t) * H);
            ra[t] = r2[lane];                                   // j = 2*lane
            rb[t] = (lane < 51) ? r2[64 + lane] : make_float2(0.f, 0.f);
        }

        // 3 groups of 4 rows: 8 independent butterfly chains per group.
#pragma unroll
        for (int g = 0; g < 3; ++g) {
            float d0[4], d1[4];
#pragma unroll
            for (int k = 0; k < 4; ++k) {
                int t = 4 * g + k;
                float t0 = fast_tanh(ra[t].x), t1 = fast_tanh(ra[t].y);
                float t2 = fast_tanh(rb[t].x), t3 = fast_tanh(rb[t].y);
                d0[k] = w0a.x * t0 + w0a.y * t1 + w0b.x * t2 + w0b.y * t3;
                d1[k] = w1a.x * t0 + w1a.y * t1 + w1b.x * t2 + w1b.y * t3;
            }
#pragma unroll
            for (int m = 32; m; m >>= 1) {
#pragma unroll
                for (int k = 0; k < 4; ++k) {
                    d0[k] += __shfl_xor(d0[k], m);
                    d1[k] += __shfl_xor(d1[k], m);
                }
            }
#pragma unroll
            for (int k = 0; k < 4; ++k) {
                int t = 4 * g + k;
                int c = cl[t];
                float e0 = __expf(d0[k] + cls[c]);
                float e1 = __expf(d1[k] + cls[NC + c]);
                z0 += e0; z1 += e1;
                sv0 += cls[2 * NC + c];
                sv1 += cls[3 * NC + c];
                acc0a.x = fmaf(e0, ra[t].x, acc0a.x);
                acc0a.y = fmaf(e0, ra[t].y, acc0a.y);
                acc0b.x = fmaf(e0, rb[t].x, acc0b.x);
                acc0b.y = fmaf(e0, rb[t].y, acc0b.y);
                acc1a.x = fmaf(e1, ra[t].x, acc1a.x);
                acc1a.y = fmaf(e1, ra[t].y, acc1a.y);
                acc1b.x = fmaf(e1, rb[t].x, acc1b.x);
                acc1b.y = fmaf(e1, rb[t].y, acc1b.y);
            }
        }
    } else {
        // Generic fallback (never taken for this problem's shapes).
        for (int i = wave; i < cnt; i += 4) {
            const float2* r2 = (const float2*)(xb + (long long)i * H);
            float2 a = r2[lane];
            float2 bb = (lane < 51) ? r2[64 + lane] : make_float2(0.f, 0.f);
            float t0 = fast_tanh(a.x), t1 = fast_tanh(a.y);
            float t2 = fast_tanh(bb.x), t3 = fast_tanh(bb.y);
            float d0 = w0a.x * t0 + w0a.y * t1 + w0b.x * t2 + w0b.y * t3;
            float d1 = w1a.x * t0 + w1a.y * t1 + w1b.x * t2 + w1b.y * t3;
#pragma unroll
            for (int m = 32; m; m >>= 1) {
                d0 += __shfl_xor(d0, m);
                d1 += __shfl_xor(d1, m);
            }
            int c = label_index[start + i];
            float e0 = __expf(d0 + cls[c]);
            float e1 = __expf(d1 + cls[NC + c]);
            z0 += e0; z1 += e1;
            sv0 += cls[2 * NC + c];
            sv1 += cls[3 * NC + c];
            acc0a.x = fmaf(e0, a.x,  acc0a.x); acc0a.y = fmaf(e0, a.y,  acc0a.y);
            acc0b.x = fmaf(e0, bb.x, acc0b.x); acc0b.y = fmaf(e0, bb.y, acc0b.y);
            acc1a.x = fmaf(e1, a.x,  acc1a.x); acc1a.y = fmaf(e1, a.y,  acc1a.y);
            acc1b.x = fmaf(e1, bb.x, acc1b.x); acc1b.y = fmaf(e1, bb.y, acc1b.y);
        }
    }

    // ---- Cross-wave merge through LDS (float2 stores, 2-way = free).
    float2* pw = (float2*)part[wave];
    pw[lane]       = acc0a;              // floats [0,128)
    pw[115 + lane] = acc1a;              // floats [230,358)
    if (lane < 51) {
        pw[64 + lane]       = acc0b;     // floats [128,230)
        pw[115 + 64 + lane] = acc1b;     // floats [358,460)
    }
    if (lane == 0) {
        zs[wave][0] = z0; zs[wave][1] = z1;
        zs[wave][2] = sv0; zs[wave][3] = sv1;
    }
    __syncthreads();

    float zt0 = zs[0][0] + zs[1][0] + zs[2][0] + zs[3][0];
    float zt1 = zs[0][1] + zs[1][1] + zs[2][1] + zs[3][1];
    float st0 = zs[0][2] + zs[1][2] + zs[2][2] + zs[3][2];
    float st1 = zs[0][3] + zs[1][3] + zs[2][3] + zs[3][3];
    float rc  = __builtin_amdgcn_rcpf((float)cnt);
    float s0  = st0 * rc * __builtin_amdgcn_rcpf(zt0);  // layer_att0 / z0
    float s1  = st1 * rc * __builtin_amdgcn_rcpf(zt1);  // layer_att1 / z1

    for (int t = tid; t < 2 * H; t += 256) {
        float s = part[0][t] + part[1][t] + part[2][t] + part[3][t];
        t01[t] = s * (t < H ? s0 : s1);
    }
    __syncthreads();

    // ---- Output projection, float4 both sides. 4 threads per class.
    int q = tid & 3;
    int c = tid >> 2;
    if (c < NC) {
        const float4* drow4 = (const float4*)(disc + c * (2 * H)); // 115 float4
        const float4* t4 = (const float4*)t01;
        float acc = 0.f;
        for (int k = q; k < 115; k += 4) {
            float4 dv = drow4[k];
            float4 tv = t4[k];
            acc += dv.x * tv.x + dv.y * tv.y + dv.z * tv.z + dv.w * tv.w;
        }
        acc += __shfl_down(acc, 2, 4);
        acc += __shfl_down(acc, 1, 4);
        if (q == 0) out[b * NC + c] = acc + bias[c];
    }
}

extern "C" void kernel_launch(void* const* d_in, const int* in_sizes, int n_in,
                              void* d_out, int out_size, void* d_ws, size_t ws_size,
                              hipStream_t stream) {
    const float* x               = (const float*)d_in[0];
    const float* rel_emb0        = (const float*)d_in[1];
    const float* rel_emb1        = (const float*)d_in[2];
    const float* att_w0          = (const float*)d_in[3];
    const float* att_w1          = (const float*)d_in[4];
    const float* w_s             = (const float*)d_in[5];
    const float* b_s             = (const float*)d_in[6];
    const float* disc            = (const float*)d_in[7];
    const float* bias            = (const float*)d_in[8];
    const int*   label_index     = (const int*)d_in[9];
    const int*   relation_levels = (const int*)d_in[10];
    const int*   scope           = (const int*)d_in[11];
    float* out = (float*)d_out;
    float* cls = (float*)d_ws;   // 4*NC floats

    class_table_kernel<<<NC, 64, 0, stream>>>(rel_emb0, rel_emb1, att_w0, att_w1,
                                              w_s, b_s, relation_levels, cls);
    bag_kernel<<<BAGS, 256, 0, stream>>>(x, w_s, disc, bias, label_index, scope,
                                         cls, out);
}